// Round 1
// baseline (202.411 us; speedup 1.0000x reference)
//
#include <hip/hip_runtime.h>

// LSTM forecast: B=1024, S=512, I=1, H=50.
// Layout: 1 block = 1 wave = 1 batch element. Lane j<50 owns the 4 gate rows
// (i,f,g,o) for hidden index j -> cell update is lane-local, no barriers in
// the 512-step recurrence. Recurrent matmul via v_dot2_f32_f16 with f16-packed
// pre-scaled weights (pack kernel writes them into d_ws each launch).

typedef _Float16 half2v __attribute__((ext_vector_type(2)));

#define LOG2E 1.44269504088896340736f
#define B_ 1024
#define S_ 512
#define H_ 50

__device__ __forceinline__ float rcp_(float x) { return __builtin_amdgcn_rcpf(x); }
__device__ __forceinline__ float ex2_(float x) { return __builtin_amdgcn_exp2f(x); }

// Pack W_hh into [gate][pair m][lane] f16-pairs, pre-scaled by the activation
// log2 factors (i,f,o: -log2e ; g: +2*log2e). Also pre-scale W_ih and the
// summed bias per (gate, lane).
__global__ void lstm_pack(const float* __restrict__ W_ih, const float* __restrict__ W_hh,
                          const float* __restrict__ b_ih, const float* __restrict__ b_hh,
                          unsigned* __restrict__ wpk, float* __restrict__ wih_pk,
                          float* __restrict__ bias_pk)
{
    int tid = blockIdx.x * blockDim.x + threadIdx.x;
    int stride = blockDim.x * gridDim.x;
    for (int p = tid; p < 4 * 25 * 64; p += stride) {
        int j = p & 63;
        int m = (p >> 6) % 25;
        int g = p / (25 * 64);
        float s = (g == 2) ? (2.0f * LOG2E) : (-LOG2E);
        float a = 0.0f, bb = 0.0f;
        if (j < H_) {
            int row = g * H_ + j;
            a  = s * W_hh[row * H_ + 2 * m];
            bb = s * W_hh[row * H_ + 2 * m + 1];
        }
        half2v hv;
        hv.x = (_Float16)a;
        hv.y = (_Float16)bb;
        wpk[p] = __builtin_bit_cast(unsigned, hv);
    }
    for (int p = tid; p < 4 * 64; p += stride) {
        int j = p & 63;
        int g = p >> 6;
        float s = (g == 2) ? (2.0f * LOG2E) : (-LOG2E);
        float wi = 0.0f, bb = 0.0f;
        if (j < H_) {
            int row = g * H_ + j;
            wi = s * W_ih[row];
            bb = s * (b_ih[row] + b_hh[row]);
        }
        wih_pk[p] = wi;
        bias_pk[p] = bb;
    }
}

__global__ __launch_bounds__(64) void lstm_main(
    const float* __restrict__ x, const float* __restrict__ h0, const float* __restrict__ c0,
    const float* __restrict__ fc_w, const float* __restrict__ fc_b,
    const unsigned* __restrict__ wpk, const float* __restrict__ wih_pk,
    const float* __restrict__ bias_pk, float* __restrict__ out)
{
    const int b = blockIdx.x;
    const int j = threadIdx.x;

    __shared__ float xs[S_];
    #pragma unroll
    for (int t = 0; t < S_ / 64; ++t) xs[j + 64 * t] = x[b * S_ + 64 * t + j];

    // Per-lane weights: 4 gates x 25 f16-pairs = 100 VGPRs. Coalesced loads.
    half2v w0[25], w1[25], w2[25], w3[25];
    #pragma unroll
    for (int m = 0; m < 25; ++m) {
        w0[m] = __builtin_bit_cast(half2v, wpk[(0 * 25 + m) * 64 + j]);
        w1[m] = __builtin_bit_cast(half2v, wpk[(1 * 25 + m) * 64 + j]);
        w2[m] = __builtin_bit_cast(half2v, wpk[(2 * 25 + m) * 64 + j]);
        w3[m] = __builtin_bit_cast(half2v, wpk[(3 * 25 + m) * 64 + j]);
    }
    float wih0 = wih_pk[0 * 64 + j], wih1 = wih_pk[1 * 64 + j];
    float wih2 = wih_pk[2 * 64 + j], wih3 = wih_pk[3 * 64 + j];
    float bs0 = bias_pk[0 * 64 + j], bs1 = bias_pk[1 * 64 + j];
    float bs2 = bias_pk[2 * 64 + j], bs3 = bias_pk[3 * 64 + j];

    float h = (j < H_) ? h0[b * H_ + j] : 0.0f;
    float c = (j < H_) ? c0[b * H_ + j] : 0.0f;

    __syncthreads();  // xs visible (single wave; cheap)

    // packed (h[2m], h[2m+1]) pairs live in even lanes
    float hn = __shfl_down(h, 1);
    unsigned hpk = __builtin_bit_cast(unsigned, __builtin_amdgcn_cvt_pkrtz(h, hn));

    for (int s = 0; s < S_; ++s) {
        float xt = xs[s];
        // gate accumulators, split A/B for ILP (even/odd pairs)
        float aA0 = __builtin_fmaf(xt, wih0, bs0);
        float aA1 = __builtin_fmaf(xt, wih1, bs1);
        float aA2 = __builtin_fmaf(xt, wih2, bs2);
        float aA3 = __builtin_fmaf(xt, wih3, bs3);
        float aB0 = 0.0f, aB1 = 0.0f, aB2 = 0.0f, aB3 = 0.0f;

        #pragma unroll
        for (int m = 0; m < 25; ++m) {
            unsigned um = (unsigned)__builtin_amdgcn_readlane((int)hpk, 2 * m);
            half2v hm = __builtin_bit_cast(half2v, um);
            if (m & 1) {
                aB0 = __builtin_amdgcn_fdot2(hm, w0[m], aB0, false);
                aB1 = __builtin_amdgcn_fdot2(hm, w1[m], aB1, false);
                aB2 = __builtin_amdgcn_fdot2(hm, w2[m], aB2, false);
                aB3 = __builtin_amdgcn_fdot2(hm, w3[m], aB3, false);
            } else {
                aA0 = __builtin_amdgcn_fdot2(hm, w0[m], aA0, false);
                aA1 = __builtin_amdgcn_fdot2(hm, w1[m], aA1, false);
                aA2 = __builtin_amdgcn_fdot2(hm, w2[m], aA2, false);
                aA3 = __builtin_amdgcn_fdot2(hm, w3[m], aA3, false);
            }
        }
        float a0 = aA0 + aB0;  // i gate, arg already = -log2e * gate
        float a1 = aA1 + aB1;  // f gate
        float a2 = aA2 + aB2;  // g gate, arg already = 2*log2e * gate
        float a3 = aA3 + aB3;  // o gate

        float ei = ex2_(a0); float si = rcp_(1.0f + ei);          // sigmoid(i)
        float ef = ex2_(a1); float sf = rcp_(1.0f + ef);          // sigmoid(f)
        float eg = ex2_(a2);
        float tg = __builtin_fmaf(-2.0f, rcp_(1.0f + eg), 1.0f);  // tanh(g)
        float eo = ex2_(a3); float so = rcp_(1.0f + eo);          // sigmoid(o)

        c = __builtin_fmaf(sf, c, si * tg);
        float ec = ex2_((2.0f * LOG2E) * c);
        float tc = __builtin_fmaf(-2.0f, rcp_(1.0f + ec), 1.0f);  // tanh(c)
        h = so * tc;

        float hnn = __shfl_down(h, 1);
        hpk = __builtin_bit_cast(unsigned, __builtin_amdgcn_cvt_pkrtz(h, hnn));
    }

    // outputs: [out (B,1)] [h_n (1,B,H)] [c_n (1,B,H)] concatenated
    if (j < H_) {
        out[B_ + b * H_ + j]            = h;
        out[B_ + B_ * H_ + b * H_ + j]  = c;
    }
    float p = (j < H_) ? h * fc_w[j] : 0.0f;
    #pragma unroll
    for (int off = 32; off > 0; off >>= 1) p += __shfl_xor(p, off);
    if (j == 0) out[b] = p + fc_b[0];
}

extern "C" void kernel_launch(void* const* d_in, const int* in_sizes, int n_in,
                              void* d_out, int out_size, void* d_ws, size_t ws_size,
                              hipStream_t stream)
{
    const float* x    = (const float*)d_in[0];
    const float* h0   = (const float*)d_in[1];
    const float* c0   = (const float*)d_in[2];
    const float* W_ih = (const float*)d_in[3];
    const float* W_hh = (const float*)d_in[4];
    const float* b_ih = (const float*)d_in[5];
    const float* b_hh = (const float*)d_in[6];
    const float* fc_w = (const float*)d_in[7];
    const float* fc_b = (const float*)d_in[8];
    float* out = (float*)d_out;

    unsigned* wpk  = (unsigned*)d_ws;                               // 6400 u32 = 25.6 KB
    float* wih_pk  = (float*)((char*)d_ws + 6400 * 4);              // 256 f32
    float* bias_pk = (float*)((char*)d_ws + 6400 * 4 + 256 * 4);    // 256 f32

    lstm_pack<<<16, 256, 0, stream>>>(W_ih, W_hh, b_ih, b_hh, wpk, wih_pk, bias_pk);
    lstm_main<<<B_, 64, 0, stream>>>(x, h0, c0, fc_w, fc_b, wpk, wih_pk, bias_pk, out);
}

// Round 2
// 199.897 us; speedup vs baseline: 1.0126x; 1.0126x over previous
//
#include <hip/hip_runtime.h>

// LSTM forecast: B=1024, S=512, I=1, H=50.
// 1 block = 1 wave = 1 batch. Lane j<50 owns gate rows (i,f,g,o) for hidden
// index j -> lane-local cell update, zero barriers in the 512-step loop.
// Recurrent matmul via v_dot2_f32_f16 on f16-packed pre-scaled weights.
// R2: __launch_bounds__(64,1) so the 100 weight VGPRs stay resident (R1 ran
// at VGPR=64 and re-fetched weights every step); x kept in 8 VGPRs and read
// via v_readlane (uniform s); h-pairing via DPP quad_perm instead of
// ds_bpermute (shfl) to shorten the per-step dependency tail.

typedef _Float16 half2v __attribute__((ext_vector_type(2)));

#define LOG2E 1.44269504088896340736f
#define B_ 1024
#define S_ 512
#define H_ 50

__device__ __forceinline__ float rcp_(float x) { return __builtin_amdgcn_rcpf(x); }
__device__ __forceinline__ float ex2_(float x) { return __builtin_amdgcn_exp2f(x); }

// Pack W_hh into [gate][pair m][lane] f16-pairs, pre-scaled by activation
// log2 factors (i,f,o: -log2e ; g: +2*log2e). Also pre-scale W_ih and biases.
__global__ void lstm_pack(const float* __restrict__ W_ih, const float* __restrict__ W_hh,
                          const float* __restrict__ b_ih, const float* __restrict__ b_hh,
                          unsigned* __restrict__ wpk, float* __restrict__ wih_pk,
                          float* __restrict__ bias_pk)
{
    int tid = blockIdx.x * blockDim.x + threadIdx.x;
    int stride = blockDim.x * gridDim.x;
    for (int p = tid; p < 4 * 25 * 64; p += stride) {
        int j = p & 63;
        int m = (p >> 6) % 25;
        int g = p / (25 * 64);
        float s = (g == 2) ? (2.0f * LOG2E) : (-LOG2E);
        float a = 0.0f, bb = 0.0f;
        if (j < H_) {
            int row = g * H_ + j;
            a  = s * W_hh[row * H_ + 2 * m];
            bb = s * W_hh[row * H_ + 2 * m + 1];
        }
        half2v hv;
        hv.x = (_Float16)a;
        hv.y = (_Float16)bb;
        wpk[p] = __builtin_bit_cast(unsigned, hv);
    }
    for (int p = tid; p < 4 * 64; p += stride) {
        int j = p & 63;
        int g = p >> 6;
        float s = (g == 2) ? (2.0f * LOG2E) : (-LOG2E);
        float wi = 0.0f, bb = 0.0f;
        if (j < H_) {
            int row = g * H_ + j;
            wi = s * W_ih[row];
            bb = s * (b_ih[row] + b_hh[row]);
        }
        wih_pk[p] = wi;
        bias_pk[p] = bb;
    }
}

__global__ __launch_bounds__(64, 1) void lstm_main(
    const float* __restrict__ x, const float* __restrict__ h0, const float* __restrict__ c0,
    const float* __restrict__ fc_w, const float* __restrict__ fc_b,
    const unsigned* __restrict__ wpk, const float* __restrict__ wih_pk,
    const float* __restrict__ bias_pk, float* __restrict__ out)
{
    const int b = blockIdx.x;
    const int j = threadIdx.x;

    // x for this batch lives in 8 VGPRs; step s reads lane (s&63) of xr[s>>6].
    int xr[S_ / 64];
    #pragma unroll
    for (int t = 0; t < S_ / 64; ++t)
        xr[t] = __builtin_bit_cast(int, x[b * S_ + 64 * t + j]);

    // Per-lane weights: 4 gates x 25 f16-pairs = 100 VGPRs. Coalesced loads.
    half2v w0[25], w1[25], w2[25], w3[25];
    #pragma unroll
    for (int m = 0; m < 25; ++m) {
        w0[m] = __builtin_bit_cast(half2v, wpk[(0 * 25 + m) * 64 + j]);
        w1[m] = __builtin_bit_cast(half2v, wpk[(1 * 25 + m) * 64 + j]);
        w2[m] = __builtin_bit_cast(half2v, wpk[(2 * 25 + m) * 64 + j]);
        w3[m] = __builtin_bit_cast(half2v, wpk[(3 * 25 + m) * 64 + j]);
    }
    float wih0 = wih_pk[0 * 64 + j], wih1 = wih_pk[1 * 64 + j];
    float wih2 = wih_pk[2 * 64 + j], wih3 = wih_pk[3 * 64 + j];
    float bs0 = bias_pk[0 * 64 + j], bs1 = bias_pk[1 * 64 + j];
    float bs2 = bias_pk[2 * 64 + j], bs3 = bias_pk[3 * 64 + j];

    float h = (j < H_) ? h0[b * H_ + j] : 0.0f;
    float c = (j < H_) ? c0[b * H_ + j] : 0.0f;

    // packed (h[2m], h[2m+1]) pairs live in even lanes; odd neighbor via DPP
    // quad_perm [1,0,3,2] (even-odd pairs never cross a quad).
    int hn_ = __builtin_amdgcn_update_dpp(0, __builtin_bit_cast(int, h),
                                          0xB1, 0xF, 0xF, true);
    unsigned hpk = __builtin_bit_cast(unsigned,
        __builtin_amdgcn_cvt_pkrtz(h, __builtin_bit_cast(float, hn_)));

    for (int s = 0; s < S_; ++s) {
        float xt = __builtin_bit_cast(float,
            __builtin_amdgcn_readlane(xr[s >> 6], s & 63));
        // gate accumulators, split A/B for ILP (even/odd pairs)
        float aA0 = __builtin_fmaf(xt, wih0, bs0);
        float aA1 = __builtin_fmaf(xt, wih1, bs1);
        float aA2 = __builtin_fmaf(xt, wih2, bs2);
        float aA3 = __builtin_fmaf(xt, wih3, bs3);
        float aB0 = 0.0f, aB1 = 0.0f, aB2 = 0.0f, aB3 = 0.0f;

        #pragma unroll
        for (int m = 0; m < 25; ++m) {
            unsigned um = (unsigned)__builtin_amdgcn_readlane((int)hpk, 2 * m);
            half2v hm = __builtin_bit_cast(half2v, um);
            if (m & 1) {
                aB0 = __builtin_amdgcn_fdot2(hm, w0[m], aB0, false);
                aB1 = __builtin_amdgcn_fdot2(hm, w1[m], aB1, false);
                aB2 = __builtin_amdgcn_fdot2(hm, w2[m], aB2, false);
                aB3 = __builtin_amdgcn_fdot2(hm, w3[m], aB3, false);
            } else {
                aA0 = __builtin_amdgcn_fdot2(hm, w0[m], aA0, false);
                aA1 = __builtin_amdgcn_fdot2(hm, w1[m], aA1, false);
                aA2 = __builtin_amdgcn_fdot2(hm, w2[m], aA2, false);
                aA3 = __builtin_amdgcn_fdot2(hm, w3[m], aA3, false);
            }
        }
        float a0 = aA0 + aB0;  // i gate, arg already = -log2e * gate
        float a1 = aA1 + aB1;  // f gate
        float a2 = aA2 + aB2;  // g gate, arg already = 2*log2e * gate
        float a3 = aA3 + aB3;  // o gate

        float ei = ex2_(a0); float si = rcp_(1.0f + ei);          // sigmoid(i)
        float ef = ex2_(a1); float sf = rcp_(1.0f + ef);          // sigmoid(f)
        float eg = ex2_(a2);
        float tg = __builtin_fmaf(-2.0f, rcp_(1.0f + eg), 1.0f);  // tanh(g)
        float eo = ex2_(a3); float so = rcp_(1.0f + eo);          // sigmoid(o)

        c = __builtin_fmaf(sf, c, si * tg);
        float ec = ex2_((2.0f * LOG2E) * c);
        float tc = __builtin_fmaf(-2.0f, rcp_(1.0f + ec), 1.0f);  // tanh(c)
        h = so * tc;

        int hnn_ = __builtin_amdgcn_update_dpp(0, __builtin_bit_cast(int, h),
                                               0xB1, 0xF, 0xF, true);
        hpk = __builtin_bit_cast(unsigned,
            __builtin_amdgcn_cvt_pkrtz(h, __builtin_bit_cast(float, hnn_)));
    }

    // outputs: [out (B,1)] [h_n (1,B,H)] [c_n (1,B,H)] concatenated
    if (j < H_) {
        out[B_ + b * H_ + j]            = h;
        out[B_ + B_ * H_ + b * H_ + j]  = c;
    }
    float p = (j < H_) ? h * fc_w[j] : 0.0f;
    #pragma unroll
    for (int off = 32; off > 0; off >>= 1) p += __shfl_xor(p, off);
    if (j == 0) out[b] = p + fc_b[0];
}

extern "C" void kernel_launch(void* const* d_in, const int* in_sizes, int n_in,
                              void* d_out, int out_size, void* d_ws, size_t ws_size,
                              hipStream_t stream)
{
    const float* x    = (const float*)d_in[0];
    const float* h0   = (const float*)d_in[1];
    const float* c0   = (const float*)d_in[2];
    const float* W_ih = (const float*)d_in[3];
    const float* W_hh = (const float*)d_in[4];
    const float* b_ih = (const float*)d_in[5];
    const float* b_hh = (const float*)d_in[6];
    const float* fc_w = (const float*)d_in[7];
    const float* fc_b = (const float*)d_in[8];
    float* out = (float*)d_out;

    unsigned* wpk  = (unsigned*)d_ws;                               // 6400 u32 = 25.6 KB
    float* wih_pk  = (float*)((char*)d_ws + 6400 * 4);              // 256 f32
    float* bias_pk = (float*)((char*)d_ws + 6400 * 4 + 256 * 4);    // 256 f32

    lstm_pack<<<16, 256, 0, stream>>>(W_ih, W_hh, b_ih, b_hh, wpk, wih_pk, bias_pk);
    lstm_main<<<B_, 64, 0, stream>>>(x, h0, c0, fc_w, fc_b, wpk, wih_pk, bias_pk, out);
}

// Round 3
// 180.177 us; speedup vs baseline: 1.1234x; 1.1094x over previous
//
#include <hip/hip_runtime.h>

// LSTM forecast: B=1024, S=512, I=1, H=50.
// 1 block = 1 wave = 1 batch. Lane j<50 owns gate rows (i,f,g,o) for hidden
// index j -> lane-local cell update, zero barriers in the 512-step loop.
// Recurrent matmul via v_dot2_f32_f16 on f16-packed pre-scaled weights.
// R3: pin the 100 weight VGPRs with asm volatile ("+v") so the compiler
// cannot rematerialize the weight loads inside the loop (R1/R2 ran at
// VGPR=64, reloading weights every step). x read as wave-uniform scalar
// load (s_load), software-pipelined one step ahead. No LDS, no scratch.

typedef _Float16 half2v __attribute__((ext_vector_type(2)));

#define LOG2E 1.44269504088896340736f
#define B_ 1024
#define S_ 512
#define H_ 50

__device__ __forceinline__ float rcp_(float x) { return __builtin_amdgcn_rcpf(x); }
__device__ __forceinline__ float ex2_(float x) { return __builtin_amdgcn_exp2f(x); }

// Pack W_hh into [gate][pair m][lane] f16-pairs, pre-scaled by activation
// log2 factors (i,f,o: -log2e ; g: +2*log2e). Also pre-scale W_ih and biases.
__global__ void lstm_pack(const float* __restrict__ W_ih, const float* __restrict__ W_hh,
                          const float* __restrict__ b_ih, const float* __restrict__ b_hh,
                          unsigned* __restrict__ wpk, float* __restrict__ wih_pk,
                          float* __restrict__ bias_pk)
{
    int tid = blockIdx.x * blockDim.x + threadIdx.x;
    int stride = blockDim.x * gridDim.x;
    for (int p = tid; p < 4 * 25 * 64; p += stride) {
        int j = p & 63;
        int m = (p >> 6) % 25;
        int g = p / (25 * 64);
        float s = (g == 2) ? (2.0f * LOG2E) : (-LOG2E);
        float a = 0.0f, bb = 0.0f;
        if (j < H_) {
            int row = g * H_ + j;
            a  = s * W_hh[row * H_ + 2 * m];
            bb = s * W_hh[row * H_ + 2 * m + 1];
        }
        half2v hv;
        hv.x = (_Float16)a;
        hv.y = (_Float16)bb;
        wpk[p] = __builtin_bit_cast(unsigned, hv);
    }
    for (int p = tid; p < 4 * 64; p += stride) {
        int j = p & 63;
        int g = p >> 6;
        float s = (g == 2) ? (2.0f * LOG2E) : (-LOG2E);
        float wi = 0.0f, bb = 0.0f;
        if (j < H_) {
            int row = g * H_ + j;
            wi = s * W_ih[row];
            bb = s * (b_ih[row] + b_hh[row]);
        }
        wih_pk[p] = wi;
        bias_pk[p] = bb;
    }
}

__global__ __launch_bounds__(64, 1) void lstm_main(
    const float* __restrict__ x, const float* __restrict__ h0, const float* __restrict__ c0,
    const float* __restrict__ fc_w, const float* __restrict__ fc_b,
    const unsigned* __restrict__ wpk, const float* __restrict__ wih_pk,
    const float* __restrict__ bias_pk, float* __restrict__ out)
{
    const int b = blockIdx.x;
    const int j = threadIdx.x;

    // Per-lane weights: 4 gates x 25 f16-pairs = 100 VGPRs. Coalesced loads.
    unsigned u0[25], u1[25], u2[25], u3[25];
    #pragma unroll
    for (int m = 0; m < 25; ++m) {
        u0[m] = wpk[(0 * 25 + m) * 64 + j];
        u1[m] = wpk[(1 * 25 + m) * 64 + j];
        u2[m] = wpk[(2 * 25 + m) * 64 + j];
        u3[m] = wpk[(3 * 25 + m) * 64 + j];
    }
    // Pin: asm output is opaque -> compiler cannot rematerialize the loads
    // inside the step loop; values get a forced live range in VGPRs.
    #pragma unroll
    for (int m = 0; m < 25; ++m) {
        asm volatile("" : "+v"(u0[m]));
        asm volatile("" : "+v"(u1[m]));
        asm volatile("" : "+v"(u2[m]));
        asm volatile("" : "+v"(u3[m]));
    }
    half2v w0[25], w1[25], w2[25], w3[25];
    #pragma unroll
    for (int m = 0; m < 25; ++m) {
        w0[m] = __builtin_bit_cast(half2v, u0[m]);
        w1[m] = __builtin_bit_cast(half2v, u1[m]);
        w2[m] = __builtin_bit_cast(half2v, u2[m]);
        w3[m] = __builtin_bit_cast(half2v, u3[m]);
    }

    float wih0 = wih_pk[0 * 64 + j], wih1 = wih_pk[1 * 64 + j];
    float wih2 = wih_pk[2 * 64 + j], wih3 = wih_pk[3 * 64 + j];
    float bs0 = bias_pk[0 * 64 + j], bs1 = bias_pk[1 * 64 + j];
    float bs2 = bias_pk[2 * 64 + j], bs3 = bias_pk[3 * 64 + j];
    asm volatile("" : "+v"(wih0), "+v"(wih1), "+v"(wih2), "+v"(wih3),
                      "+v"(bs0), "+v"(bs1), "+v"(bs2), "+v"(bs3));

    float h = (j < H_) ? h0[b * H_ + j] : 0.0f;
    float c = (j < H_) ? c0[b * H_ + j] : 0.0f;

    // packed (h[2m], h[2m+1]) pairs live in even lanes; odd neighbor via DPP
    // quad_perm [1,0,3,2] (even-odd pairs never cross a quad).
    int hn_ = __builtin_amdgcn_update_dpp(0, __builtin_bit_cast(int, h),
                                          0xB1, 0xF, 0xF, true);
    unsigned hpk = __builtin_bit_cast(unsigned,
        __builtin_amdgcn_cvt_pkrtz(h, __builtin_bit_cast(float, hn_)));

    // x row: wave-uniform scalar loads, software-pipelined 1 step ahead.
    const float* __restrict__ xrow = x + b * S_;
    float xt = xrow[0];

    for (int s = 0; s < S_; ++s) {
        int sn = s + 1 < S_ ? s + 1 : S_ - 1;
        float xt_n = xrow[sn];

        // gate accumulators, split A/B for ILP (even/odd pairs)
        float aA0 = __builtin_fmaf(xt, wih0, bs0);
        float aA1 = __builtin_fmaf(xt, wih1, bs1);
        float aA2 = __builtin_fmaf(xt, wih2, bs2);
        float aA3 = __builtin_fmaf(xt, wih3, bs3);
        float aB0 = 0.0f, aB1 = 0.0f, aB2 = 0.0f, aB3 = 0.0f;

        #pragma unroll
        for (int m = 0; m < 25; ++m) {
            unsigned um = (unsigned)__builtin_amdgcn_readlane((int)hpk, 2 * m);
            half2v hm = __builtin_bit_cast(half2v, um);
            if (m & 1) {
                aB0 = __builtin_amdgcn_fdot2(hm, w0[m], aB0, false);
                aB1 = __builtin_amdgcn_fdot2(hm, w1[m], aB1, false);
                aB2 = __builtin_amdgcn_fdot2(hm, w2[m], aB2, false);
                aB3 = __builtin_amdgcn_fdot2(hm, w3[m], aB3, false);
            } else {
                aA0 = __builtin_amdgcn_fdot2(hm, w0[m], aA0, false);
                aA1 = __builtin_amdgcn_fdot2(hm, w1[m], aA1, false);
                aA2 = __builtin_amdgcn_fdot2(hm, w2[m], aA2, false);
                aA3 = __builtin_amdgcn_fdot2(hm, w3[m], aA3, false);
            }
        }
        float a0 = aA0 + aB0;  // i gate, arg already = -log2e * gate
        float a1 = aA1 + aB1;  // f gate
        float a2 = aA2 + aB2;  // g gate, arg already = 2*log2e * gate
        float a3 = aA3 + aB3;  // o gate

        float ei = ex2_(a0); float si = rcp_(1.0f + ei);          // sigmoid(i)
        float ef = ex2_(a1); float sf = rcp_(1.0f + ef);          // sigmoid(f)
        float eg = ex2_(a2);
        float tg = __builtin_fmaf(-2.0f, rcp_(1.0f + eg), 1.0f);  // tanh(g)
        float eo = ex2_(a3); float so = rcp_(1.0f + eo);          // sigmoid(o)

        c = __builtin_fmaf(sf, c, si * tg);
        float ec = ex2_((2.0f * LOG2E) * c);
        float tc = __builtin_fmaf(-2.0f, rcp_(1.0f + ec), 1.0f);  // tanh(c)
        h = so * tc;

        int hnn_ = __builtin_amdgcn_update_dpp(0, __builtin_bit_cast(int, h),
                                               0xB1, 0xF, 0xF, true);
        hpk = __builtin_bit_cast(unsigned,
            __builtin_amdgcn_cvt_pkrtz(h, __builtin_bit_cast(float, hnn_)));
        xt = xt_n;
    }

    // outputs: [out (B,1)] [h_n (1,B,H)] [c_n (1,B,H)] concatenated
    if (j < H_) {
        out[B_ + b * H_ + j]            = h;
        out[B_ + B_ * H_ + b * H_ + j]  = c;
    }
    float p = (j < H_) ? h * fc_w[j] : 0.0f;
    #pragma unroll
    for (int off = 32; off > 0; off >>= 1) p += __shfl_xor(p, off);
    if (j == 0) out[b] = p + fc_b[0];
}

extern "C" void kernel_launch(void* const* d_in, const int* in_sizes, int n_in,
                              void* d_out, int out_size, void* d_ws, size_t ws_size,
                              hipStream_t stream)
{
    const float* x    = (const float*)d_in[0];
    const float* h0   = (const float*)d_in[1];
    const float* c0   = (const float*)d_in[2];
    const float* W_ih = (const float*)d_in[3];
    const float* W_hh = (const float*)d_in[4];
    const float* b_ih = (const float*)d_in[5];
    const float* b_hh = (const float*)d_in[6];
    const float* fc_w = (const float*)d_in[7];
    const float* fc_b = (const float*)d_in[8];
    float* out = (float*)d_out;

    unsigned* wpk  = (unsigned*)d_ws;                               // 6400 u32 = 25.6 KB
    float* wih_pk  = (float*)((char*)d_ws + 6400 * 4);              // 256 f32
    float* bias_pk = (float*)((char*)d_ws + 6400 * 4 + 256 * 4);    // 256 f32

    lstm_pack<<<16, 256, 0, stream>>>(W_ih, W_hh, b_ih, b_hh, wpk, wih_pk, bias_pk);
    lstm_main<<<B_, 64, 0, stream>>>(x, h0, c0, fc_w, fc_b, wpk, wih_pk, bias_pk, out);
}